// Round 10
// baseline (849.214 us; speedup 1.0000x reference)
//
#include <hip/hip_runtime.h>
#include <math.h>

#define D 128

typedef __attribute__((ext_vector_type(8))) short short8;
typedef __attribute__((ext_vector_type(4))) float float4v;

__device__ __forceinline__ unsigned short f2bf(float x) {
    unsigned u = __float_as_uint(x);
    u += ((u >> 16) & 1u) + 0x7fffu;          // RNE
    return (unsigned short)(u >> 16);
}
__device__ __forceinline__ float bf2f(unsigned short h) {
    return __uint_as_float((unsigned)h << 16);
}

// ---------------- CSR build (XCD-partitioned: blockIdx%8 -> dst range) ----------------

__global__ void k_count(const int* __restrict__ ei, int E, int N, int* deg) {
    int part = blockIdx.x & 7;
    int slice = blockIdx.x >> 3;
    int nsl = gridDim.x >> 3;
    int lo = (int)((long long)N * part >> 3);
    int hi = (int)((long long)N * (part + 1) >> 3);
    const int* dst = ei + E;
    for (int i = slice * blockDim.x + threadIdx.x; i < E; i += nsl * blockDim.x) {
        int d = dst[i];
        if (d >= lo && d < hi) atomicAdd(&deg[d], 1);
    }
}

__global__ void k_scan1(const int* __restrict__ deg, int N, int* tmp, int* bsum) {
    __shared__ int sh[256];
    int t = threadIdx.x;
    int i = blockIdx.x * 256 + t;
    int v = (i < N) ? deg[i] : 0;
    sh[t] = v;
    __syncthreads();
    for (int o = 1; o < 256; o <<= 1) {
        int u = (t >= o) ? sh[t - o] : 0;
        __syncthreads();
        sh[t] += u;
        __syncthreads();
    }
    if (i < N) tmp[i] = sh[t] - v;          // exclusive
    if (t == 255) bsum[blockIdx.x] = sh[255];
}

__global__ void k_scan2(int* bsum, int B) {
    __shared__ int sh[256];
    int t = threadIdx.x;
    int v = (t < B) ? bsum[t] : 0;
    sh[t] = v;
    __syncthreads();
    for (int o = 1; o < 256; o <<= 1) {
        int u = (t >= o) ? sh[t - o] : 0;
        __syncthreads();
        sh[t] += u;
        __syncthreads();
    }
    bsum[t] = sh[t] - v;
}

__global__ void k_scan3(const int* __restrict__ tmp, const int* __restrict__ bscan,
                        int N, int total, int* rowptr, int* fill) {
    int i = blockIdx.x * blockDim.x + threadIdx.x;
    if (i < N) {
        int r = tmp[i] + bscan[i >> 8];
        rowptr[i] = r;
        fill[i] = r;
    }
    if (i == 0) rowptr[N] = total;
}

__global__ void k_fill(const int* __restrict__ ei, int E, int N, int* fill, int* csr) {
    int part = blockIdx.x & 7;
    int slice = blockIdx.x >> 3;
    int nsl = gridDim.x >> 3;
    int lo = (int)((long long)N * part >> 3);
    int hi = (int)((long long)N * (part + 1) >> 3);
    int total = E + N;
    const int* dst = ei + E;
    for (int i = slice * blockDim.x + threadIdx.x; i < total; i += nsl * blockDim.x) {
        int d_ = (i < E) ? dst[i] : i - E;
        if (d_ >= lo && d_ < hi) {
            int s_ = (i < E) ? ei[i] : i - E;    // src read only when in-partition
            int p = atomicAdd(&fill[d_], 1);
            csr[p] = s_;
        }
    }
}

// ---------------- prep: W pack (3 layers) + deg init, one launch ---------------------
// wpack tile (ct,kt): lane holds W[k=kt*32+(lane>>4)*8+j][n=ct*16+(lane&15)], j=0..7

__global__ void k_prep(const float* __restrict__ W0, const float* __restrict__ W1,
                       const float* __restrict__ W2, unsigned short* __restrict__ whi,
                       unsigned short* __restrict__ wlo, int* __restrict__ deg, int N) {
    int id = blockIdx.x * blockDim.x + threadIdx.x;
    if (id < 6144) {
        int l = id >> 11;
        int id2 = id & 2047;
        const float* W = (l == 0) ? W0 : (l == 1) ? W1 : W2;
        int lane = id2 & 63;
        int tile = id2 >> 6;          // ct*4 + kt
        int kt = tile & 3;
        int ct = tile >> 2;
        int k0 = kt * 32 + (lane >> 4) * 8;
        int n  = ct * 16 + (lane & 15);
        size_t base = (size_t)l * 16384 + (size_t)id2 * 8;
        for (int j = 0; j < 8; j++) {
            float w = W[(k0 + j) * D + n];
            unsigned short h = f2bf(w);
            whi[base + j] = h;
            wlo[base + j] = f2bf(w - bf2f(h));
        }
    } else {
        int i = id - 6144;
        if (i < N) deg[i] = 1;        // self-loop pre-counted
    }
}

// ---------------- persistent-W MFMA GEMM (bf16x4 split = fp32 accuracy) --------------
// 512 thr = 8 waves; W (64 KB) staged in LDS ONCE per block, then grid-stride loop
// over 128-row tiles with NO barrier (W read-only) -> A-loads of tile t+1 overlap
// MFMA of tile t across waves. Wave = 16 rows x 128 cols, A straight from global.

template <bool EXP>
__global__ __launch_bounds__(512, 4) void k_gemm(const float* __restrict__ A,
                                                 const unsigned short* __restrict__ Whi,
                                                 const unsigned short* __restrict__ Wlo,
                                                 const float* __restrict__ avS,
                                                 const float* __restrict__ avD,
                                                 float* __restrict__ H,
                                                 float* __restrict__ sA,
                                                 float* __restrict__ dA, int N) {
    __shared__ unsigned short WshHi[16384];   // 32 KB
    __shared__ unsigned short WshLo[16384];   // 32 KB
    int t = threadIdx.x;
    int wv = t >> 6, lane = t & 63, quad = lane >> 4, m = lane & 15;

    {   // stage W hi/lo into LDS (fully coalesced, once per block)
        const uint4* gh = (const uint4*)Whi;
        const uint4* gl = (const uint4*)Wlo;
        uint4* sh = (uint4*)WshHi;
        uint4* sl = (uint4*)WshLo;
#pragma unroll
        for (int i = 0; i < 4; i++) {
            sh[i * 512 + t] = gh[i * 512 + t];
            sl[i * 512 + t] = gl[i * 512 + t];
        }
    }
    __syncthreads();

    const int TILES = (N + 127) >> 7;
    for (int rt = blockIdx.x; rt < TILES; rt += gridDim.x) {
        int rg = rt * 128 + wv * 16 + m;             // this lane's A row
        bool valid = rg < N;
        const float* arow = &A[(size_t)(valid ? rg : 0) * D];

        short8 ahi[4], alo[4];
        if (EXP) {
            float af[32];
#pragma unroll
            for (int kt = 0; kt < 4; kt++) {
                int k0 = kt * 32 + quad * 8;
                float4 x0 = valid ? *(const float4*)&arow[k0]     : make_float4(0.f, 0.f, 0.f, 0.f);
                float4 x1 = valid ? *(const float4*)&arow[k0 + 4] : make_float4(0.f, 0.f, 0.f, 0.f);
                af[kt * 8 + 0] = x0.x; af[kt * 8 + 1] = x0.y; af[kt * 8 + 2] = x0.z; af[kt * 8 + 3] = x0.w;
                af[kt * 8 + 4] = x1.x; af[kt * 8 + 5] = x1.y; af[kt * 8 + 6] = x1.z; af[kt * 8 + 7] = x1.w;
            }
            float ss = 0.f;
#pragma unroll
            for (int q = 0; q < 32; q++) ss += af[q] * af[q];
            ss += __shfl_xor(ss, 16, 64);
            ss += __shfl_xor(ss, 32, 64);
            float n = fmaxf(sqrtf(ss), 1e-15f);
            float sc = tanhf(n) / n;
#pragma unroll
            for (int kt = 0; kt < 4; kt++) {
#pragma unroll
                for (int j = 0; j < 8; j++) {
                    float v = af[kt * 8 + j] * sc;
                    unsigned short h = f2bf(v);
                    ahi[kt][j] = (short)h;
                    alo[kt][j] = (short)f2bf(v - bf2f(h));
                }
            }
        } else {
#pragma unroll
            for (int kt = 0; kt < 4; kt++) {
                int k0 = kt * 32 + quad * 8;
                float4 x0 = valid ? *(const float4*)&arow[k0]     : make_float4(0.f, 0.f, 0.f, 0.f);
                float4 x1 = valid ? *(const float4*)&arow[k0 + 4] : make_float4(0.f, 0.f, 0.f, 0.f);
                float v0[8] = {x0.x, x0.y, x0.z, x0.w, x1.x, x1.y, x1.z, x1.w};
#pragma unroll
                for (int j = 0; j < 8; j++) {
                    unsigned short h = f2bf(v0[j]);
                    ahi[kt][j] = (short)h;
                    alo[kt][j] = (short)f2bf(v0[j] - bf2f(h));
                }
            }
        }

        float4v acc[8];
#pragma unroll
        for (int ct = 0; ct < 8; ct++) acc[ct] = (float4v){0.f, 0.f, 0.f, 0.f};

#pragma unroll
        for (int kt = 0; kt < 4; kt++) {
#pragma unroll
            for (int ct = 0; ct < 8; ct++) {
                int wofs = (((ct << 2) | kt) * 64 + lane) * 8;
                short8 whi = *(const short8*)&WshHi[wofs];
                short8 wlo = *(const short8*)&WshLo[wofs];
                acc[ct] = __builtin_amdgcn_mfma_f32_16x16x32_bf16(alo[kt], wlo, acc[ct], 0, 0, 0);
                acc[ct] = __builtin_amdgcn_mfma_f32_16x16x32_bf16(alo[kt], whi, acc[ct], 0, 0, 0);
                acc[ct] = __builtin_amdgcn_mfma_f32_16x16x32_bf16(ahi[kt], wlo, acc[ct], 0, 0, 0);
                acc[ct] = __builtin_amdgcn_mfma_f32_16x16x32_bf16(ahi[kt], whi, acc[ct], 0, 0, 0);
            }
        }

        // store H (C/D layout: col=m, row=quad*4+r)
        int growbase = rt * 128 + wv * 16 + quad * 4;
#pragma unroll
        for (int r = 0; r < 4; r++) {
            int gr = growbase + r;
            if (gr < N) {
#pragma unroll
                for (int ct = 0; ct < 8; ct++)
                    H[(size_t)gr * D + ct * 16 + m] = acc[ct][r];
            }
        }

        // fused dots: reduce over the 16 lanes of each quad
        float ps[4] = {0, 0, 0, 0}, pd[4] = {0, 0, 0, 0};
#pragma unroll
        for (int ct = 0; ct < 8; ct++) {
            float as_v = avS[ct * 16 + m];
            float ad_v = avD[ct * 16 + m];
#pragma unroll
            for (int r = 0; r < 4; r++) {
                ps[r] += acc[ct][r] * as_v;
                pd[r] += acc[ct][r] * ad_v;
            }
        }
        for (int o = 1; o < 16; o <<= 1) {
#pragma unroll
            for (int r = 0; r < 4; r++) {
                ps[r] += __shfl_xor(ps[r], o, 64);
                pd[r] += __shfl_xor(pd[r], o, 64);
            }
        }
        if (m == 0) {
#pragma unroll
            for (int r = 0; r < 4; r++) {
                int gr = growbase + r;
                if (gr < N) { sA[gr] = ps[r]; dA[gr] = pd[r]; }
            }
        }
    }
}

// ---------------- fused softmax + aggregation: one wave per dst ----------------------

template <bool ACT>
__global__ __launch_bounds__(256) void k_agg(const float* __restrict__ H,
                                             const float* __restrict__ sA,
                                             const float* __restrict__ dA,
                                             const int* __restrict__ rowptr,
                                             const int* __restrict__ csr,
                                             const float* __restrict__ bias,
                                             float* __restrict__ out, int N) {
    int lane = threadIdx.x & 63;
    int node = blockIdx.x * 4 + (threadIdx.x >> 6);
    if (node >= N) return;
    int start = __builtin_amdgcn_readfirstlane(rowptr[node]);
    int end   = __builtin_amdgcn_readfirstlane(rowptr[node + 1]);
    float di  = dA[node];
    int half  = lane >> 5;
    int cq    = (lane & 31) * 4;

    float ax = 0.f, ay = 0.f, az = 0.f, aw = 0.f;
    float den = 0.f;
    int j = start;
    for (; j + 4 <= end; j += 4) {
        int s0 = csr[j + 0], s1 = csr[j + 1], s2 = csr[j + 2], s3 = csr[j + 3];
        float e0 = sA[s0] + di, e1 = sA[s1] + di, e2 = sA[s2] + di, e3 = sA[s3] + di;
        e0 = (e0 > 0.f) ? e0 : 0.2f * e0;
        e1 = (e1 > 0.f) ? e1 : 0.2f * e1;
        e2 = (e2 > 0.f) ? e2 : 0.2f * e2;
        e3 = (e3 > 0.f) ? e3 : 0.2f * e3;
        float p0 = __expf(e0), p1 = __expf(e1), p2 = __expf(e2), p3 = __expf(e3);
        int   sa = half ? s1 : s0;
        int   sb = half ? s3 : s2;
        float wa = half ? p1 : p0;
        float wb = half ? p3 : p2;
        den += wa + wb;
        float4 ha = *(const float4*)&H[(size_t)sa * D + cq];
        float4 hb = *(const float4*)&H[(size_t)sb * D + cq];
        ax += wa * ha.x + wb * hb.x;
        ay += wa * ha.y + wb * hb.y;
        az += wa * ha.z + wb * hb.z;
        aw += wa * ha.w + wb * hb.w;
    }
    if (j + 2 <= end) {
        int s0 = csr[j + 0], s1 = csr[j + 1];
        float e0 = sA[s0] + di, e1 = sA[s1] + di;
        e0 = (e0 > 0.f) ? e0 : 0.2f * e0;
        e1 = (e1 > 0.f) ? e1 : 0.2f * e1;
        float p0 = __expf(e0), p1 = __expf(e1);
        int   sa = half ? s1 : s0;
        float wa = half ? p1 : p0;
        den += wa;
        float4 ha = *(const float4*)&H[(size_t)sa * D + cq];
        ax += wa * ha.x; ay += wa * ha.y; az += wa * ha.z; aw += wa * ha.w;
        j += 2;
    }
    if (j < end && half == 0) {
        int s0 = csr[j];
        float e0 = sA[s0] + di;
        e0 = (e0 > 0.f) ? e0 : 0.2f * e0;
        float p0 = __expf(e0);
        den += p0;
        float4 ha = *(const float4*)&H[(size_t)s0 * D + cq];
        ax += p0 * ha.x; ay += p0 * ha.y; az += p0 * ha.z; aw += p0 * ha.w;
    }

    ax  += __shfl_xor(ax, 32, 64);
    ay  += __shfl_xor(ay, 32, 64);
    az  += __shfl_xor(az, 32, 64);
    aw  += __shfl_xor(aw, 32, 64);
    den += __shfl_xor(den, 32, 64);

    if (half == 0) {
        float iv = 1.f / den;
        float4 b4 = *(const float4*)&bias[cq];
        float vx = ax * iv + b4.x;
        float vy = ay * iv + b4.y;
        float vz = az * iv + b4.z;
        float vw = aw * iv + b4.w;
        if (ACT) {
            vx = 2.f * tanhf(vx);
            vy = 2.f * tanhf(vy);
            vz = 2.f * tanhf(vz);
            vw = 2.f * tanhf(vw);
        }
        *(float4*)&out[(size_t)node * D + cq] = make_float4(vx, vy, vz, vw);
    }
}

// ---------------- launch ----------------

extern "C" void kernel_launch(void* const* d_in, const int* in_sizes, int n_in,
                              void* d_out, int out_size, void* d_ws, size_t ws_size,
                              hipStream_t stream) {
    const int N = in_sizes[0] / D;
    const int E = in_sizes[1] / 2;
    const float* x = (const float*)d_in[0];
    const int* ei = (const int*)d_in[1];
    const float* Wm[3] = {(const float*)d_in[2], (const float*)d_in[6], (const float*)d_in[10]};
    const float* aS[3] = {(const float*)d_in[3], (const float*)d_in[7], (const float*)d_in[11]};
    const float* aD[3] = {(const float*)d_in[4], (const float*)d_in[8], (const float*)d_in[12]};
    const float* bb[3] = {(const float*)d_in[5], (const float*)d_in[9], (const float*)d_in[13]};

    char* ws = (char*)d_ws;
    size_t off = 0;
    auto alloc = [&](size_t bytes) -> void* {
        void* p = ws + off;
        off = (off + bytes + 511) & ~(size_t)511;
        return p;
    };
    float* bufA  = (float*)alloc((size_t)N * D * 4);
    float* bufB  = (float*)alloc((size_t)N * D * 4);
    float* sArr  = (float*)alloc((size_t)N * 4);
    float* dArr  = (float*)alloc((size_t)N * 4);
    int*   deg   = (int*)alloc((size_t)N * 4);
    int*   rowptr= (int*)alloc((size_t)(N + 1) * 4);
    int*   tmp   = (int*)alloc((size_t)N * 4);
    int*   bsum  = (int*)alloc(256 * 4);
    int*   csr   = (int*)alloc((size_t)(E + N) * 4);
    unsigned short* whiB = (unsigned short*)alloc((size_t)3 * D * D * 2);
    unsigned short* wloB = (unsigned short*)alloc((size_t)3 * D * D * 2);
    (void)ws_size; (void)n_in; (void)out_size;

    const int B1 = (N + 255) / 256;

    k_prep<<<(6144 + N + 255) / 256, 256, 0, stream>>>(Wm[0], Wm[1], Wm[2],
                                                       whiB, wloB, deg, N);
    k_count<<<1024, 256, 0, stream>>>(ei, E, N, deg);
    k_scan1<<<B1, 256, 0, stream>>>(deg, N, tmp, bsum);
    k_scan2<<<1, 256, 0, stream>>>(bsum, B1);
    k_scan3<<<B1, 256, 0, stream>>>(tmp, bsum, N, E + N, rowptr, deg);
    k_fill<<<1024, 256, 0, stream>>>(ei, E, N, deg, csr);

    for (int l = 0; l < 3; l++) {
        const unsigned short* whi = whiB + (size_t)l * 16384;
        const unsigned short* wlo = wloB + (size_t)l * 16384;
        if (l == 0) {
            k_gemm<true><<<256, 512, 0, stream>>>(x, whi, wlo, aS[0], aD[0],
                                                  bufB, sArr, dArr, N);
        } else {
            k_gemm<false><<<256, 512, 0, stream>>>(bufA, whi, wlo, aS[l], aD[l],
                                                   bufB, sArr, dArr, N);
        }
        if (l < 2) {
            k_agg<true><<<(N + 3) / 4, 256, 0, stream>>>(bufB, sArr, dArr, rowptr, csr,
                                                         bb[l], bufA, N);
        } else {
            k_agg<false><<<(N + 3) / 4, 256, 0, stream>>>(bufB, sArr, dArr, rowptr, csr,
                                                          bb[l], (float*)d_out, N);
        }
    }
}

// Round 11
// 619.835 us; speedup vs baseline: 1.3701x; 1.3701x over previous
//
#include <hip/hip_runtime.h>
#include <math.h>

#define D 128

typedef __attribute__((ext_vector_type(8))) short short8;
typedef __attribute__((ext_vector_type(4))) float float4v;

__device__ __forceinline__ unsigned short f2bf(float x) {
    unsigned u = __float_as_uint(x);
    u += ((u >> 16) & 1u) + 0x7fffu;          // RNE
    return (unsigned short)(u >> 16);
}
__device__ __forceinline__ float bf2f(unsigned short h) {
    return __uint_as_float((unsigned)h << 16);
}

// ---------------- CSR build (XCD-partitioned: blockIdx%8 -> dst range) ----------------

__global__ void k_count(const int* __restrict__ ei, int E, int N, int* deg) {
    int part = blockIdx.x & 7;
    int slice = blockIdx.x >> 3;
    int nsl = gridDim.x >> 3;
    int lo = (int)((long long)N * part >> 3);
    int hi = (int)((long long)N * (part + 1) >> 3);
    const int* dst = ei + E;
    for (int i = slice * blockDim.x + threadIdx.x; i < E; i += nsl * blockDim.x) {
        int d = dst[i];
        if (d >= lo && d < hi) atomicAdd(&deg[d], 1);
    }
}

__global__ void k_scan1(const int* __restrict__ deg, int N, int* tmp, int* bsum) {
    __shared__ int sh[256];
    int t = threadIdx.x;
    int i = blockIdx.x * 256 + t;
    int v = (i < N) ? deg[i] : 0;
    sh[t] = v;
    __syncthreads();
    for (int o = 1; o < 256; o <<= 1) {
        int u = (t >= o) ? sh[t - o] : 0;
        __syncthreads();
        sh[t] += u;
        __syncthreads();
    }
    if (i < N) tmp[i] = sh[t] - v;          // exclusive
    if (t == 255) bsum[blockIdx.x] = sh[255];
}

__global__ void k_scan2(int* bsum, int B) {
    __shared__ int sh[256];
    int t = threadIdx.x;
    int v = (t < B) ? bsum[t] : 0;
    sh[t] = v;
    __syncthreads();
    for (int o = 1; o < 256; o <<= 1) {
        int u = (t >= o) ? sh[t - o] : 0;
        __syncthreads();
        sh[t] += u;
        __syncthreads();
    }
    bsum[t] = sh[t] - v;
}

__global__ void k_scan3(const int* __restrict__ tmp, const int* __restrict__ bscan,
                        int N, int total, int* rowptr, int* fill) {
    int i = blockIdx.x * blockDim.x + threadIdx.x;
    if (i < N) {
        int r = tmp[i] + bscan[i >> 8];
        rowptr[i] = r;
        fill[i] = r;
    }
    if (i == 0) rowptr[N] = total;
}

__global__ void k_fill(const int* __restrict__ ei, int E, int N, int* fill, int* csr) {
    int part = blockIdx.x & 7;
    int slice = blockIdx.x >> 3;
    int nsl = gridDim.x >> 3;
    int lo = (int)((long long)N * part >> 3);
    int hi = (int)((long long)N * (part + 1) >> 3);
    int total = E + N;
    const int* dst = ei + E;
    for (int i = slice * blockDim.x + threadIdx.x; i < total; i += nsl * blockDim.x) {
        int d_ = (i < E) ? dst[i] : i - E;
        if (d_ >= lo && d_ < hi) {
            int s_ = (i < E) ? ei[i] : i - E;    // src read only when in-partition
            int p = atomicAdd(&fill[d_], 1);
            csr[p] = s_;
        }
    }
}

// ---------------- prep: W pack (3 layers) + deg init, one launch ---------------------
// wpack tile (ct,kt): lane holds W[k=kt*32+(lane>>4)*8+j][n=ct*16+(lane&15)], j=0..7

__global__ void k_prep(const float* __restrict__ W0, const float* __restrict__ W1,
                       const float* __restrict__ W2, unsigned short* __restrict__ whi,
                       unsigned short* __restrict__ wlo, int* __restrict__ deg, int N) {
    int id = blockIdx.x * blockDim.x + threadIdx.x;
    if (id < 6144) {
        int l = id >> 11;
        int id2 = id & 2047;
        const float* W = (l == 0) ? W0 : (l == 1) ? W1 : W2;
        int lane = id2 & 63;
        int tile = id2 >> 6;          // ct*4 + kt
        int kt = tile & 3;
        int ct = tile >> 2;
        int k0 = kt * 32 + (lane >> 4) * 8;
        int n  = ct * 16 + (lane & 15);
        size_t base = (size_t)l * 16384 + (size_t)id2 * 8;
        for (int j = 0; j < 8; j++) {
            float w = W[(k0 + j) * D + n];
            unsigned short h = f2bf(w);
            whi[base + j] = h;
            wlo[base + j] = f2bf(w - bf2f(h));
        }
    } else {
        int i = id - 6144;
        if (i < N) deg[i] = 1;        // self-loop pre-counted
    }
}

// ---------------- MFMA GEMM (R9 shape): W hi/lo in LDS, A in registers ---------------
// bf16x4 split = fp32 accuracy. 256 thr, 64-row blocks. NO min-occupancy bound
// (R10 lesson: __launch_bounds__(512,4) forced VGPR=64 -> scratch spills, 180MB writes).

template <bool EXP>
__global__ __launch_bounds__(256) void k_gemm(const float* __restrict__ A,
                                              const unsigned short* __restrict__ Whi,
                                              const unsigned short* __restrict__ Wlo,
                                              const float* __restrict__ avS,
                                              const float* __restrict__ avD,
                                              float* __restrict__ H,
                                              float* __restrict__ sA,
                                              float* __restrict__ dA, int N) {
    __shared__ unsigned short WshHi[16384];   // 32 KB
    __shared__ unsigned short WshLo[16384];   // 32 KB
    int t = threadIdx.x;
    int wv = t >> 6, lane = t & 63, quad = lane >> 4, m = lane & 15;

    {   // stage W hi/lo into LDS (fully coalesced)
        const uint4* gh = (const uint4*)Whi;
        const uint4* gl = (const uint4*)Wlo;
        uint4* sh = (uint4*)WshHi;
        uint4* sl = (uint4*)WshLo;
#pragma unroll
        for (int i = 0; i < 8; i++) {
            sh[i * 256 + t] = gh[i * 256 + t];
            sl[i * 256 + t] = gl[i * 256 + t];
        }
    }

    int rg = blockIdx.x * 64 + wv * 16 + m;          // this lane's A row
    bool valid = rg < N;
    const float* arow = &A[(size_t)(valid ? rg : 0) * D];

    float af[32];
#pragma unroll
    for (int kt = 0; kt < 4; kt++) {
        int k0 = kt * 32 + quad * 8;
        float4 x0 = valid ? *(const float4*)&arow[k0]     : make_float4(0.f, 0.f, 0.f, 0.f);
        float4 x1 = valid ? *(const float4*)&arow[k0 + 4] : make_float4(0.f, 0.f, 0.f, 0.f);
        af[kt * 8 + 0] = x0.x; af[kt * 8 + 1] = x0.y; af[kt * 8 + 2] = x0.z; af[kt * 8 + 3] = x0.w;
        af[kt * 8 + 4] = x1.x; af[kt * 8 + 5] = x1.y; af[kt * 8 + 6] = x1.z; af[kt * 8 + 7] = x1.w;
    }

    if (EXP) {
        float ss = 0.f;
#pragma unroll
        for (int q = 0; q < 32; q++) ss += af[q] * af[q];
        ss += __shfl_xor(ss, 16, 64);
        ss += __shfl_xor(ss, 32, 64);
        float n = fmaxf(sqrtf(ss), 1e-15f);
        float sc = tanhf(n) / n;
#pragma unroll
        for (int q = 0; q < 32; q++) af[q] *= sc;
    }

    short8 ahi[4], alo[4];
#pragma unroll
    for (int kt = 0; kt < 4; kt++) {
#pragma unroll
        for (int j = 0; j < 8; j++) {
            float v = af[kt * 8 + j];
            unsigned short h = f2bf(v);
            ahi[kt][j] = (short)h;
            alo[kt][j] = (short)f2bf(v - bf2f(h));
        }
    }

    __syncthreads();

    float4v acc[8];
#pragma unroll
    for (int ct = 0; ct < 8; ct++) acc[ct] = (float4v){0.f, 0.f, 0.f, 0.f};

#pragma unroll
    for (int kt = 0; kt < 4; kt++) {
#pragma unroll
        for (int ct = 0; ct < 8; ct++) {
            int wofs = (((ct << 2) | kt) * 64 + lane) * 8;
            short8 whi = *(const short8*)&WshHi[wofs];
            short8 wlo = *(const short8*)&WshLo[wofs];
            acc[ct] = __builtin_amdgcn_mfma_f32_16x16x32_bf16(alo[kt], wlo, acc[ct], 0, 0, 0);
            acc[ct] = __builtin_amdgcn_mfma_f32_16x16x32_bf16(alo[kt], whi, acc[ct], 0, 0, 0);
            acc[ct] = __builtin_amdgcn_mfma_f32_16x16x32_bf16(ahi[kt], wlo, acc[ct], 0, 0, 0);
            acc[ct] = __builtin_amdgcn_mfma_f32_16x16x32_bf16(ahi[kt], whi, acc[ct], 0, 0, 0);
        }
    }

    // store H (C/D layout: col=m, row=quad*4+r)
    int growbase = blockIdx.x * 64 + wv * 16 + quad * 4;
#pragma unroll
    for (int r = 0; r < 4; r++) {
        int gr = growbase + r;
        if (gr < N) {
#pragma unroll
            for (int ct = 0; ct < 8; ct++)
                H[(size_t)gr * D + ct * 16 + m] = acc[ct][r];
        }
    }

    // fused dots: reduce over the 16 lanes of each quad
    float ps[4] = {0, 0, 0, 0}, pd[4] = {0, 0, 0, 0};
#pragma unroll
    for (int ct = 0; ct < 8; ct++) {
        float as_v = avS[ct * 16 + m];
        float ad_v = avD[ct * 16 + m];
#pragma unroll
        for (int r = 0; r < 4; r++) {
            ps[r] += acc[ct][r] * as_v;
            pd[r] += acc[ct][r] * ad_v;
        }
    }
    for (int o = 1; o < 16; o <<= 1) {
#pragma unroll
        for (int r = 0; r < 4; r++) {
            ps[r] += __shfl_xor(ps[r], o, 64);
            pd[r] += __shfl_xor(pd[r], o, 64);
        }
    }
    if (m == 0) {
#pragma unroll
        for (int r = 0; r < 4; r++) {
            int gr = growbase + r;
            if (gr < N) { sA[gr] = ps[r]; dA[gr] = pd[r]; }
        }
    }
}

// ---------------- fused softmax + aggregation: one wave per dst ----------------------
// 8 edges per main-loop iteration: each half-wave gathers 4 H rows (4 independent
// float4 loads/lane) -> 2x memory concurrency vs R9 (latency-bound regime).

template <bool ACT>
__global__ __launch_bounds__(256) void k_agg(const float* __restrict__ H,
                                             const float* __restrict__ sA,
                                             const float* __restrict__ dA,
                                             const int* __restrict__ rowptr,
                                             const int* __restrict__ csr,
                                             const float* __restrict__ bias,
                                             float* __restrict__ out, int N) {
    int lane = threadIdx.x & 63;
    int node = blockIdx.x * 4 + (threadIdx.x >> 6);
    if (node >= N) return;
    int start = __builtin_amdgcn_readfirstlane(rowptr[node]);
    int end   = __builtin_amdgcn_readfirstlane(rowptr[node + 1]);
    float di  = dA[node];
    int half  = lane >> 5;
    int cq    = (lane & 31) * 4;

    float ax = 0.f, ay = 0.f, az = 0.f, aw = 0.f;
    float den = 0.f;
    int j = start;

    for (; j + 8 <= end; j += 8) {
        int s0 = csr[j + 0], s1 = csr[j + 1], s2 = csr[j + 2], s3 = csr[j + 3];
        int s4 = csr[j + 4], s5 = csr[j + 5], s6 = csr[j + 6], s7 = csr[j + 7];
        float e0 = sA[s0] + di, e1 = sA[s1] + di, e2 = sA[s2] + di, e3 = sA[s3] + di;
        float e4 = sA[s4] + di, e5 = sA[s5] + di, e6 = sA[s6] + di, e7 = sA[s7] + di;
        e0 = (e0 > 0.f) ? e0 : 0.2f * e0;
        e1 = (e1 > 0.f) ? e1 : 0.2f * e1;
        e2 = (e2 > 0.f) ? e2 : 0.2f * e2;
        e3 = (e3 > 0.f) ? e3 : 0.2f * e3;
        e4 = (e4 > 0.f) ? e4 : 0.2f * e4;
        e5 = (e5 > 0.f) ? e5 : 0.2f * e5;
        e6 = (e6 > 0.f) ? e6 : 0.2f * e6;
        e7 = (e7 > 0.f) ? e7 : 0.2f * e7;
        float p0 = __expf(e0), p1 = __expf(e1), p2 = __expf(e2), p3 = __expf(e3);
        float p4 = __expf(e4), p5 = __expf(e5), p6 = __expf(e6), p7 = __expf(e7);
        // half 0: edges 0,2,4,6 ; half 1: edges 1,3,5,7
        int   ra = half ? s1 : s0;
        int   rb = half ? s3 : s2;
        int   rc = half ? s5 : s4;
        int   rd = half ? s7 : s6;
        float wa = half ? p1 : p0;
        float wb = half ? p3 : p2;
        float wc = half ? p5 : p4;
        float wd = half ? p7 : p6;
        float4 ha = *(const float4*)&H[(size_t)ra * D + cq];
        float4 hb = *(const float4*)&H[(size_t)rb * D + cq];
        float4 hc = *(const float4*)&H[(size_t)rc * D + cq];
        float4 hd = *(const float4*)&H[(size_t)rd * D + cq];
        den += (wa + wb) + (wc + wd);
        ax += wa * ha.x + wb * hb.x + wc * hc.x + wd * hd.x;
        ay += wa * ha.y + wb * hb.y + wc * hc.y + wd * hd.y;
        az += wa * ha.z + wb * hb.z + wc * hc.z + wd * hd.z;
        aw += wa * ha.w + wb * hb.w + wc * hc.w + wd * hd.w;
    }
    if (j + 4 <= end) {
        int s0 = csr[j + 0], s1 = csr[j + 1], s2 = csr[j + 2], s3 = csr[j + 3];
        float e0 = sA[s0] + di, e1 = sA[s1] + di, e2 = sA[s2] + di, e3 = sA[s3] + di;
        e0 = (e0 > 0.f) ? e0 : 0.2f * e0;
        e1 = (e1 > 0.f) ? e1 : 0.2f * e1;
        e2 = (e2 > 0.f) ? e2 : 0.2f * e2;
        e3 = (e3 > 0.f) ? e3 : 0.2f * e3;
        float p0 = __expf(e0), p1 = __expf(e1), p2 = __expf(e2), p3 = __expf(e3);
        int   ra = half ? s1 : s0;
        int   rb = half ? s3 : s2;
        float wa = half ? p1 : p0;
        float wb = half ? p3 : p2;
        float4 ha = *(const float4*)&H[(size_t)ra * D + cq];
        float4 hb = *(const float4*)&H[(size_t)rb * D + cq];
        den += wa + wb;
        ax += wa * ha.x + wb * hb.x;
        ay += wa * ha.y + wb * hb.y;
        az += wa * ha.z + wb * hb.z;
        aw += wa * ha.w + wb * hb.w;
        j += 4;
    }
    if (j + 2 <= end) {
        int s0 = csr[j + 0], s1 = csr[j + 1];
        float e0 = sA[s0] + di, e1 = sA[s1] + di;
        e0 = (e0 > 0.f) ? e0 : 0.2f * e0;
        e1 = (e1 > 0.f) ? e1 : 0.2f * e1;
        float p0 = __expf(e0), p1 = __expf(e1);
        int   ra = half ? s1 : s0;
        float wa = half ? p1 : p0;
        den += wa;
        float4 ha = *(const float4*)&H[(size_t)ra * D + cq];
        ax += wa * ha.x; ay += wa * ha.y; az += wa * ha.z; aw += wa * ha.w;
        j += 2;
    }
    if (j < end && half == 0) {
        int s0 = csr[j];
        float e0 = sA[s0] + di;
        e0 = (e0 > 0.f) ? e0 : 0.2f * e0;
        float p0 = __expf(e0);
        den += p0;
        float4 ha = *(const float4*)&H[(size_t)s0 * D + cq];
        ax += p0 * ha.x; ay += p0 * ha.y; az += p0 * ha.z; aw += p0 * ha.w;
    }

    ax  += __shfl_xor(ax, 32, 64);
    ay  += __shfl_xor(ay, 32, 64);
    az  += __shfl_xor(az, 32, 64);
    aw  += __shfl_xor(aw, 32, 64);
    den += __shfl_xor(den, 32, 64);

    if (half == 0) {
        float iv = 1.f / den;
        float4 b4 = *(const float4*)&bias[cq];
        float vx = ax * iv + b4.x;
        float vy = ay * iv + b4.y;
        float vz = az * iv + b4.z;
        float vw = aw * iv + b4.w;
        if (ACT) {
            vx = 2.f * tanhf(vx);
            vy = 2.f * tanhf(vy);
            vz = 2.f * tanhf(vz);
            vw = 2.f * tanhf(vw);
        }
        *(float4*)&out[(size_t)node * D + cq] = make_float4(vx, vy, vz, vw);
    }
}

// ---------------- launch ----------------

extern "C" void kernel_launch(void* const* d_in, const int* in_sizes, int n_in,
                              void* d_out, int out_size, void* d_ws, size_t ws_size,
                              hipStream_t stream) {
    const int N = in_sizes[0] / D;
    const int E = in_sizes[1] / 2;
    const float* x = (const float*)d_in[0];
    const int* ei = (const int*)d_in[1];
    const float* Wm[3] = {(const float*)d_in[2], (const float*)d_in[6], (const float*)d_in[10]};
    const float* aS[3] = {(const float*)d_in[3], (const float*)d_in[7], (const float*)d_in[11]};
    const float* aD[3] = {(const float*)d_in[4], (const float*)d_in[8], (const float*)d_in[12]};
    const float* bb[3] = {(const float*)d_in[5], (const float*)d_in[9], (const float*)d_in[13]};

    char* ws = (char*)d_ws;
    size_t off = 0;
    auto alloc = [&](size_t bytes) -> void* {
        void* p = ws + off;
        off = (off + bytes + 511) & ~(size_t)511;
        return p;
    };
    float* bufA  = (float*)alloc((size_t)N * D * 4);
    float* bufB  = (float*)alloc((size_t)N * D * 4);
    float* sArr  = (float*)alloc((size_t)N * 4);
    float* dArr  = (float*)alloc((size_t)N * 4);
    int*   deg   = (int*)alloc((size_t)N * 4);
    int*   rowptr= (int*)alloc((size_t)(N + 1) * 4);
    int*   tmp   = (int*)alloc((size_t)N * 4);
    int*   bsum  = (int*)alloc(256 * 4);
    int*   csr   = (int*)alloc((size_t)(E + N) * 4);
    unsigned short* whiB = (unsigned short*)alloc((size_t)3 * D * D * 2);
    unsigned short* wloB = (unsigned short*)alloc((size_t)3 * D * D * 2);
    (void)ws_size; (void)n_in; (void)out_size;

    const int B1 = (N + 255) / 256;

    k_prep<<<(6144 + N + 255) / 256, 256, 0, stream>>>(Wm[0], Wm[1], Wm[2],
                                                       whiB, wloB, deg, N);
    k_count<<<1024, 256, 0, stream>>>(ei, E, N, deg);
    k_scan1<<<B1, 256, 0, stream>>>(deg, N, tmp, bsum);
    k_scan2<<<1, 256, 0, stream>>>(bsum, B1);
    k_scan3<<<B1, 256, 0, stream>>>(tmp, bsum, N, E + N, rowptr, deg);
    k_fill<<<1024, 256, 0, stream>>>(ei, E, N, deg, csr);

    const int gemmBlocks = (N + 63) / 64;
    for (int l = 0; l < 3; l++) {
        const unsigned short* whi = whiB + (size_t)l * 16384;
        const unsigned short* wlo = wloB + (size_t)l * 16384;
        if (l == 0) {
            k_gemm<true><<<gemmBlocks, 256, 0, stream>>>(x, whi, wlo, aS[0], aD[0],
                                                         bufB, sArr, dArr, N);
        } else {
            k_gemm<false><<<gemmBlocks, 256, 0, stream>>>(bufA, whi, wlo, aS[l], aD[l],
                                                          bufB, sArr, dArr, N);
        }
        if (l < 2) {
            k_agg<true><<<(N + 3) / 4, 256, 0, stream>>>(bufB, sArr, dArr, rowptr, csr,
                                                         bb[l], bufA, N);
        } else {
            k_agg<false><<<(N + 3) / 4, 256, 0, stream>>>(bufB, sArr, dArr, rowptr, csr,
                                                          bb[l], (float*)d_out, N);
        }
    }
}